// Round 2
// baseline (198.045 us; speedup 1.0000x reference)
//
#include <hip/hip_runtime.h>
#include <stdint.h>

// Problem constants (match reference)
constexpr int BB      = 4;
constexpr int NN      = 8192;
constexpr int NPOINT  = 2048;
constexpr int CC      = 64;
constexpr int NSAMPLE = 32;
constexpr int KTOT    = NSAMPLE + 1;   // fps_idx prepended -> 33
constexpr int NCH     = 3 + 3 + CC;    // 70 output channels

// ---------------------------------------------------------------------------
// Kernel 1: ball query. One wave (64 lanes) per centroid. Scans the N points
// in ascending order, 64 at a time; ballot + popcount-prefix assigns in-order
// slots for the first NSAMPLE in-radius indices. Slots beyond the hit count
// are padded with the first in-radius index (0 if none). Slot 0 = fps_idx.
// d2 uses __f*_rn intrinsics (NO fma contraction) and numpy's sum order
// ((dx^2 + dy^2) + dz^2) to bit-match the fp32 reference at d2 < r^2.
// ---------------------------------------------------------------------------
__global__ __launch_bounds__(256) void ball_query_kernel(
    const float* __restrict__ xyz,      // (B, N, 3)
    const float* __restrict__ new_xyz,  // (B, NPOINT, 3)
    const int*   __restrict__ fps_idx,  // (B, NPOINT)
    int*         __restrict__ idx_out)  // (B*NPOINT, KTOT)
{
    const int wave = (blockIdx.x * blockDim.x + threadIdx.x) >> 6;
    const int lane = threadIdx.x & 63;
    if (wave >= BB * NPOINT) return;
    const int b = wave / NPOINT;
    const int j = wave - b * NPOINT;

    const float* cptr = new_xyz + (size_t)(b * NPOINT + j) * 3;
    const float cx = cptr[0];
    const float cy = cptr[1];
    const float cz = cptr[2];
    const float r2 = __fmul_rn(0.1f, 0.1f);   // fp32(0.1)^2, matches jnp.float32(0.1)**2

    const float* xb = xyz + (size_t)b * NN * 3;
    int* out = idx_out + (size_t)wave * KTOT;

    int count = 0;    // wave-uniform
    int first = 0;    // wave-uniform: first in-radius index

    const unsigned long long below = (lane == 0) ? 0ull : (~0ull >> (64 - lane));

    for (int base = 0; base < NN; base += 64) {
        const int p = base + lane;
        const float x = xb[p * 3 + 0];
        const float y = xb[p * 3 + 1];
        const float z = xb[p * 3 + 2];
        const float dx = __fsub_rn(cx, x);
        const float dy = __fsub_rn(cy, y);
        const float dz = __fsub_rn(cz, z);
        const float d2 = __fadd_rn(__fadd_rn(__fmul_rn(dx, dx), __fmul_rn(dy, dy)),
                                   __fmul_rn(dz, dz));
        const bool valid = d2 < r2;
        const unsigned long long mask = __ballot(valid);
        if (count == 0 && mask != 0ull) {
            first = base + __builtin_ctzll(mask);   // wave-uniform
        }
        const int slot = count + __popcll(mask & below);
        if (valid && slot < NSAMPLE) {
            out[1 + slot] = p;
        }
        count += __popcll(mask);
        if (count >= NSAMPLE) break;   // uniform branch (mask is wave-uniform)
    }

    if (count < NSAMPLE) {
        const int pad = (count > 0) ? first : 0;
        if (lane >= count && lane < NSAMPLE) out[1 + lane] = pad;
    }
    if (lane == 0) out[0] = fps_idx[b * NPOINT + j];
}

// ---------------------------------------------------------------------------
// Kernel 2: gather + center + concat. One thread per output element.
// out shape (B, 70, NPOINT, 33): ch 0-2 centered xyz, ch 3-5 centered xyz
// (duplicate), ch 6-69 gathered features. Stores are fully coalesced fp32.
// ---------------------------------------------------------------------------
__global__ __launch_bounds__(256) void gather_kernel(
    const float* __restrict__ xyz,       // (B, N, 3)
    const float* __restrict__ new_xyz,   // (B, NPOINT, 3)
    const float* __restrict__ features,  // (B, C, N)
    const int*   __restrict__ idx,       // (B*NPOINT, KTOT)
    float*       __restrict__ out)       // (B, 70, NPOINT, 33)
{
    const long long total = (long long)BB * NCH * NPOINT * KTOT;
    const long long o = (long long)blockIdx.x * blockDim.x + threadIdx.x;
    if (o >= total) return;

    const int s  = (int)(o % KTOT);
    long long t  = o / KTOT;
    const int j  = (int)(t % NPOINT);
    t /= NPOINT;
    const int ch = (int)(t % NCH);
    const int b  = (int)(t / NCH);

    const int id = idx[(long long)(b * NPOINT + j) * KTOT + s];

    float v;
    if (ch < 6) {
        const int c3 = (ch >= 3) ? (ch - 3) : ch;
        const float g = xyz[((long long)b * NN + id) * 3 + c3];
        const float c = new_xyz[((long long)b * NPOINT + j) * 3 + c3];
        v = __fsub_rn(g, c);
    } else {
        v = features[((long long)b * CC + (ch - 6)) * NN + id];
    }
    out[o] = v;
}

extern "C" void kernel_launch(void* const* d_in, const int* in_sizes, int n_in,
                              void* d_out, int out_size, void* d_ws, size_t ws_size,
                              hipStream_t stream) {
    const float* xyz      = (const float*)d_in[0];
    const float* new_xyz  = (const float*)d_in[1];
    const float* features = (const float*)d_in[2];
    const int*   fps_idx  = (const int*)d_in[3];
    float*       out      = (float*)d_out;
    int*         idxbuf   = (int*)d_ws;   // B*NPOINT*KTOT int32 ~= 1.03 MB

    // Stage 1: ball query. One wave per centroid, 4 waves per block.
    const int nwaves = BB * NPOINT;                 // 8192
    ball_query_kernel<<<nwaves / 4, 256, 0, stream>>>(xyz, new_xyz, fps_idx, idxbuf);

    // Stage 2: gather/center/concat. One thread per output element.
    const long long total = (long long)BB * NCH * NPOINT * KTOT;  // 18,923,520
    const int blocks = (int)((total + 255) / 256);
    gather_kernel<<<blocks, 256, 0, stream>>>(xyz, new_xyz, features, idxbuf, out);
}